// Round 6
// baseline (368.050 us; speedup 1.0000x reference)
//
#include <hip/hip_runtime.h>
#include <math.h>

#define KBINS 8
#define R_MIN -5.0f
#define R_MAX 5.0f
#define MIN_BIN 1e-4f
#define MIN_SLOPE 1e-4f

typedef float v4f __attribute__((ext_vector_type(4)));

// d_ws float layout:
// [0..8]    x_pos (9)   (ws[1..7] = interior edges; wave-uniform -> s_load)
// [9..17]   y_pos (9)
// [18..26]  slopes (9)
// [28..91]  per-bin table, 8 floats (32 B) per bin, bin b at 28+8b:
//           {x_k, 1/width, y_k, height, s, slope_k, slope_k1, c0=sk+sk1-2s}
//           32 B stride: worst case 2-way LDS conflict = free on CDNA4 (m136).
// [92]      log(slopes[0])
// [93]      log(slopes[K])

__global__ void rqs_params_kernel(const float* __restrict__ p, float* __restrict__ ws) {
    if (threadIdx.x != 0 || blockIdx.x != 0) return;
    float w[KBINS], h[KBINS], sl[KBINS + 1];
    const float scale = (R_MAX - R_MIN) - KBINS * MIN_BIN;

    float m = -1e30f;
    for (int i = 0; i < KBINS; ++i) m = fmaxf(m, p[i]);
    float sum = 0.f;
    for (int i = 0; i < KBINS; ++i) { w[i] = expf(p[i] - m); sum += w[i]; }
    for (int i = 0; i < KBINS; ++i) w[i] = w[i] / sum * scale + MIN_BIN;

    m = -1e30f;
    for (int i = 0; i < KBINS; ++i) m = fmaxf(m, p[KBINS + i]);
    sum = 0.f;
    for (int i = 0; i < KBINS; ++i) { h[i] = expf(p[KBINS + i] - m); sum += h[i]; }
    for (int i = 0; i < KBINS; ++i) h[i] = h[i] / sum * scale + MIN_BIN;

    const float off = logf(expf(1.0f - MIN_SLOPE) - 1.0f);
    for (int i = 0; i <= KBINS; ++i) {
        float z = p[2 * KBINS + i] + off;
        float sp = (z > 20.f) ? z : log1pf(expf(z));
        sl[i] = sp + MIN_SLOPE;
    }

    float xp[KBINS + 1], yp[KBINS + 1];
    xp[0] = R_MIN; yp[0] = R_MIN;
    for (int i = 0; i < KBINS; ++i) { xp[i + 1] = xp[i] + w[i]; yp[i + 1] = yp[i] + h[i]; }

    for (int i = 0; i <= KBINS; ++i) {
        ws[i] = xp[i];
        ws[9 + i] = yp[i];
        ws[18 + i] = sl[i];
    }
    for (int b = 0; b < KBINS; ++b) {
        float width  = xp[b + 1] - xp[b];
        float height = yp[b + 1] - yp[b];
        float s = height / width;
        float* q = ws + 28 + b * 8;
        q[0] = xp[b];
        q[1] = 1.0f / width;
        q[2] = yp[b];
        q[3] = height;
        q[4] = s;
        q[5] = sl[b];
        q[6] = sl[b + 1];
        q[7] = sl[b] + sl[b + 1] - 2.0f * s;   // c0
    }
    ws[92] = logf(sl[0]);
    ws[93] = logf(sl[KBINS]);
}

__device__ __forceinline__ void rqs_elem(
        float x, const v4f* __restrict__ sbin,
        float e1, float e2, float e3, float e4, float e5, float e6, float e7,
        float sl0, float slK, float lsl0, float lslK,
        float& y_out, float& ld_out) {
    // searchsorted(x_pos[1:-1], x, 'right') == count(edge <= x)
    int b = (int)(x >= e1) + (int)(x >= e2) + (int)(x >= e3) + (int)(x >= e4)
          + (int)(x >= e5) + (int)(x >= e6) + (int)(x >= e7);

    const v4f q0 = sbin[2 * b];       // {xk, invw, yk, h}
    const v4f q1 = sbin[2 * b + 1];   // {s, sk, sk1, c0}

    float xi = (x - q0[0]) * q0[1];
    xi = fminf(fmaxf(xi, 0.f), 1.f);
    const float s = q1[0], sk = q1[1], sk1 = q1[2], c0 = q1[3];
    const float xi1m = 1.f - xi;
    const float xx   = xi * xi1m;
    const float xi2  = xi * xi;
    const float num  = s * xi2 + sk * xx;
    const float den  = s + c0 * xx;
    const float invd = __builtin_amdgcn_rcpf(den);
    float y = q0[2] + q0[3] * (num * invd);
    const float dnum  = (s * s) * (sk1 * xi2 + 2.f * s * xx + sk * (xi1m * xi1m));
    const float deriv = dnum * (invd * invd);
    float ld = __logf(deriv);

    const bool below = x < R_MIN;
    const bool above = x > R_MAX;
    const float yl = (x - R_MIN) * sl0 + R_MIN;
    const float yr = (x - R_MAX) * slK + R_MAX;
    y  = above ? yr  : y;
    y  = below ? yl  : y;
    ld = above ? lslK : ld;
    ld = below ? lsl0 : ld;

    y_out = y;
    ld_out = ld;
}

#define NBLK 2048   // G11: memory-bound -> ~2048 blocks + grid-stride.
                    // 2048*256*16 = 8388608 = n4 exactly (16 iters/thread, no tail).

__global__ __launch_bounds__(256) void rqs_main_kernel(
        const v4f* __restrict__ x4,
        const float*  __restrict__ ws,
        v4f* __restrict__ y4,
        v4f* __restrict__ ld4,
        int n4) {
    __shared__ __align__(16) v4f sbin[2 * KBINS];

    const int tid = threadIdx.x;
    if (tid < 2 * KBINS) sbin[tid] = ((const v4f*)(ws + 28))[tid];
    __syncthreads();

    // wave-uniform -> s_load; hoisted once for all 16 iterations
    const float e1 = ws[1], e2 = ws[2], e3 = ws[3], e4 = ws[4],
                e5 = ws[5], e6 = ws[6], e7 = ws[7];
    const float sl0 = ws[18], slK = ws[26];
    const float lsl0 = ws[92], lslK = ws[93];

    const int stride = gridDim.x * blockDim.x;      // 524288
    int i = blockIdx.x * blockDim.x + tid;
    if (i >= n4) return;

    v4f xv = x4[i];                                  // prime the pipeline
    for (;;) {
        const int nxt = i + stride;
        const bool has = nxt < n4;
        v4f xnext;
        if (has) xnext = x4[nxt];                    // load k+1 in flight during compute k

        v4f yv, lv;
        #pragma unroll
        for (int j = 0; j < 4; ++j) {
            float yt, lt;
            rqs_elem(xv[j], sbin, e1, e2, e3, e4, e5, e6, e7,
                     sl0, slK, lsl0, lslK, yt, lt);
            yv[j] = yt; lv[j] = lt;
        }
        y4[i]  = yv;
        ld4[i] = lv;

        if (!has) break;
        i = nxt;
        xv = xnext;
    }
}

extern "C" void kernel_launch(void* const* d_in, const int* in_sizes, int n_in,
                              void* d_out, int out_size, void* d_ws, size_t ws_size,
                              hipStream_t stream) {
    const float* x = (const float*)d_in[0];
    const float* p = (const float*)d_in[1];
    float* out = (float*)d_out;
    float* ws  = (float*)d_ws;
    const int N = in_sizes[0];
    const int n4 = N / 4;   // N = 33554432, divisible by 4

    rqs_params_kernel<<<1, 64, 0, stream>>>(p, ws);
    rqs_main_kernel<<<NBLK, 256, 0, stream>>>(
        (const v4f*)x, ws, (v4f*)out, (v4f*)out + n4, n4);
}

// Round 7
// 367.269 us; speedup vs baseline: 1.0021x; 1.0021x over previous
//
#include <hip/hip_runtime.h>
#include <math.h>

#define KBINS 8
#define R_MIN -5.0f
#define R_MAX 5.0f
#define MIN_BIN 1e-4f
#define MIN_SLOPE 1e-4f

typedef float v4f __attribute__((ext_vector_type(4)));

// d_ws float layout:
// [0..8]    x_pos (9)   (ws[1..7] = interior edges; wave-uniform -> s_load)
// [9..17]   y_pos (9)
// [18..26]  slopes (9)
// [28..91]  per-bin table, 8 floats (32 B) per bin, bin b at 28+8b:
//           {x_k, 1/width, y_k, height, s, slope_k, slope_k1, c0=sk+sk1-2s}
//           32 B stride: worst case 2-way LDS conflict = free on CDNA4 (m136).
// [92]      log(slopes[0])
// [93]      log(slopes[K])

__global__ void rqs_params_kernel(const float* __restrict__ p, float* __restrict__ ws) {
    if (threadIdx.x != 0 || blockIdx.x != 0) return;
    float w[KBINS], h[KBINS], sl[KBINS + 1];
    const float scale = (R_MAX - R_MIN) - KBINS * MIN_BIN;

    float m = -1e30f;
    for (int i = 0; i < KBINS; ++i) m = fmaxf(m, p[i]);
    float sum = 0.f;
    for (int i = 0; i < KBINS; ++i) { w[i] = expf(p[i] - m); sum += w[i]; }
    for (int i = 0; i < KBINS; ++i) w[i] = w[i] / sum * scale + MIN_BIN;

    m = -1e30f;
    for (int i = 0; i < KBINS; ++i) m = fmaxf(m, p[KBINS + i]);
    sum = 0.f;
    for (int i = 0; i < KBINS; ++i) { h[i] = expf(p[KBINS + i] - m); sum += h[i]; }
    for (int i = 0; i < KBINS; ++i) h[i] = h[i] / sum * scale + MIN_BIN;

    const float off = logf(expf(1.0f - MIN_SLOPE) - 1.0f);
    for (int i = 0; i <= KBINS; ++i) {
        float z = p[2 * KBINS + i] + off;
        float sp = (z > 20.f) ? z : log1pf(expf(z));
        sl[i] = sp + MIN_SLOPE;
    }

    float xp[KBINS + 1], yp[KBINS + 1];
    xp[0] = R_MIN; yp[0] = R_MIN;
    for (int i = 0; i < KBINS; ++i) { xp[i + 1] = xp[i] + w[i]; yp[i + 1] = yp[i] + h[i]; }

    for (int i = 0; i <= KBINS; ++i) {
        ws[i] = xp[i];
        ws[9 + i] = yp[i];
        ws[18 + i] = sl[i];
    }
    for (int b = 0; b < KBINS; ++b) {
        float width  = xp[b + 1] - xp[b];
        float height = yp[b + 1] - yp[b];
        float s = height / width;
        float* q = ws + 28 + b * 8;
        q[0] = xp[b];
        q[1] = 1.0f / width;
        q[2] = yp[b];
        q[3] = height;
        q[4] = s;
        q[5] = sl[b];
        q[6] = sl[b + 1];
        q[7] = sl[b] + sl[b + 1] - 2.0f * s;   // c0
    }
    ws[92] = logf(sl[0]);
    ws[93] = logf(sl[KBINS]);
}

__device__ __forceinline__ void rqs_elem(
        float x, const v4f* __restrict__ sbin,
        float e1, float e2, float e3, float e4, float e5, float e6, float e7,
        float sl0, float slK, float lsl0, float lslK,
        float& y_out, float& ld_out) {
    // searchsorted(x_pos[1:-1], x, 'right') == count(edge <= x)
    int b = (int)(x >= e1) + (int)(x >= e2) + (int)(x >= e3) + (int)(x >= e4)
          + (int)(x >= e5) + (int)(x >= e6) + (int)(x >= e7);

    const v4f q0 = sbin[2 * b];       // {xk, invw, yk, h}
    const v4f q1 = sbin[2 * b + 1];   // {s, sk, sk1, c0}

    float xi = (x - q0[0]) * q0[1];
    xi = fminf(fmaxf(xi, 0.f), 1.f);
    const float s = q1[0], sk = q1[1], sk1 = q1[2], c0 = q1[3];
    const float xi1m = 1.f - xi;
    const float xx   = xi * xi1m;
    const float xi2  = xi * xi;
    const float num  = s * xi2 + sk * xx;
    const float den  = s + c0 * xx;
    const float invd = __builtin_amdgcn_rcpf(den);
    float y = q0[2] + q0[3] * (num * invd);
    const float dnum  = (s * s) * (sk1 * xi2 + 2.f * s * xx + sk * (xi1m * xi1m));
    const float deriv = dnum * (invd * invd);
    float ld = __logf(deriv);

    const bool below = x < R_MIN;
    const bool above = x > R_MAX;
    const float yl = (x - R_MIN) * sl0 + R_MIN;
    const float yr = (x - R_MAX) * slK + R_MAX;
    y  = above ? yr  : y;
    y  = below ? yl  : y;
    ld = above ? lslK : ld;
    ld = below ? lsl0 : ld;

    y_out = y;
    ld_out = ld;
}

// ---- grid-stride variant with compile-time trip count, no runtime guards ----
// GS_BLOCKS*256*GS_ITERS = 4096*256*8 = 8388608 = n4 exactly for N = 33554432.
// Fully unrolled; every x-prefetch (distance 2) is issued BEFORE the current
// iteration's stores, so the consuming s_waitcnt can be vmcnt(N>0): store
// completions never land on the critical path.
#define GS_BLOCKS 4096
#define GS_ITERS  8

__global__ __launch_bounds__(256) void rqs_main_gs(
        const v4f* __restrict__ x4,
        const float*  __restrict__ ws,
        v4f* __restrict__ y4,
        v4f* __restrict__ ld4) {
    __shared__ __align__(16) v4f sbin[2 * KBINS];

    const int tid = threadIdx.x;
    if (tid < 2 * KBINS) sbin[tid] = ((const v4f*)(ws + 28))[tid];
    __syncthreads();

    const float e1 = ws[1], e2 = ws[2], e3 = ws[3], e4 = ws[4],
                e5 = ws[5], e6 = ws[6], e7 = ws[7];
    const float sl0 = ws[18], slK = ws[26];
    const float lsl0 = ws[92], lslK = ws[93];

    const int stride = GS_BLOCKS * 256;
    int i = blockIdx.x * 256 + tid;

    v4f xa = x4[i];                 // iter 0
    v4f xb = x4[i + stride];        // iter 1

    #pragma unroll
    for (int k = 0; k < GS_ITERS; k += 2) {
        v4f xna, xnb;
        if (k + 2 < GS_ITERS) xna = x4[i + 2 * stride];   // compile-time guard
        {
            v4f yv, lv;
            #pragma unroll
            for (int j = 0; j < 4; ++j) {
                float yt, lt;
                rqs_elem(xa[j], sbin, e1, e2, e3, e4, e5, e6, e7,
                         sl0, slK, lsl0, lslK, yt, lt);
                yv[j] = yt; lv[j] = lt;
            }
            y4[i]  = yv;
            ld4[i] = lv;
        }
        if (k + 3 < GS_ITERS) xnb = x4[i + 3 * stride];   // compile-time guard
        {
            v4f yv, lv;
            #pragma unroll
            for (int j = 0; j < 4; ++j) {
                float yt, lt;
                rqs_elem(xb[j], sbin, e1, e2, e3, e4, e5, e6, e7,
                         sl0, slK, lsl0, lslK, yt, lt);
                yv[j] = yt; lv[j] = lt;
            }
            y4[i + stride]  = yv;
            ld4[i + stride] = lv;
        }
        xa = xna; xb = xnb;
        i += 2 * stride;
    }
}

// ---- fallback: the proven R5 structure for any other N ----
__global__ __launch_bounds__(256) void rqs_main_kernel(
        const v4f* __restrict__ x4,
        const float*  __restrict__ ws,
        v4f* __restrict__ y4,
        v4f* __restrict__ ld4,
        int n4) {
    __shared__ __align__(16) v4f sbin[2 * KBINS];

    const int tid = threadIdx.x;
    if (tid < 2 * KBINS) sbin[tid] = ((const v4f*)(ws + 28))[tid];
    __syncthreads();

    const int i = blockIdx.x * blockDim.x + tid;
    if (i >= n4) return;

    const float e1 = ws[1], e2 = ws[2], e3 = ws[3], e4 = ws[4],
                e5 = ws[5], e6 = ws[6], e7 = ws[7];
    const float sl0 = ws[18], slK = ws[26];
    const float lsl0 = ws[92], lslK = ws[93];

    const v4f xv = x4[i];
    v4f yv, lv;

    #pragma unroll
    for (int j = 0; j < 4; ++j) {
        float yt, lt;
        rqs_elem(xv[j], sbin, e1, e2, e3, e4, e5, e6, e7,
                 sl0, slK, lsl0, lslK, yt, lt);
        yv[j] = yt; lv[j] = lt;
    }

    y4[i]  = yv;
    ld4[i] = lv;
}

extern "C" void kernel_launch(void* const* d_in, const int* in_sizes, int n_in,
                              void* d_out, int out_size, void* d_ws, size_t ws_size,
                              hipStream_t stream) {
    const float* x = (const float*)d_in[0];
    const float* p = (const float*)d_in[1];
    float* out = (float*)d_out;
    float* ws  = (float*)d_ws;
    const int N = in_sizes[0];
    const int n4 = N / 4;

    rqs_params_kernel<<<1, 64, 0, stream>>>(p, ws);

    if (n4 == GS_BLOCKS * 256 * GS_ITERS) {
        rqs_main_gs<<<GS_BLOCKS, 256, 0, stream>>>(
            (const v4f*)x, ws, (v4f*)out, (v4f*)out + n4);
    } else {
        rqs_main_kernel<<<(n4 + 255) / 256, 256, 0, stream>>>(
            (const v4f*)x, ws, (v4f*)out, (v4f*)out + n4, n4);
    }
}